// Round 16
// baseline (182.562 us; speedup 1.0000x reference)
//
#include <hip/hip_runtime.h>

#define B_ 2
#define T_ 2048
#define C_ 1024
#define H_ 16
#define DH_ 64

typedef __attribute__((ext_vector_type(8))) _Float16 half8;  // 8 f16 (4 VGPRs)
typedef __attribute__((ext_vector_type(4))) _Float16 half4;  // 4 f16 (2 VGPRs)
typedef __attribute__((ext_vector_type(2))) __fp16 fp16x2;   // cvt_pkrtz result type
typedef __attribute__((ext_vector_type(4))) float f32x4;

__device__ __forceinline__ unsigned short f2h(float f) {
    union { _Float16 h; unsigned short u; } cv; cv.h = (_Float16)f; return cv.u;
}
__device__ __forceinline__ unsigned pk2(float a, float b) {
    union { fp16x2 h; unsigned u; } cv;
    cv.h = __builtin_amdgcn_cvt_pkrtz(a, b);
    return cv.u;
}

__device__ __forceinline__ void gll16(const void* g, void* l) {
    __builtin_amdgcn_global_load_lds(
        (const __attribute__((address_space(1))) void*)g,
        (__attribute__((address_space(3))) void*)l, 16, 0, 0);
}

// K frag-packed: chunk (kt, c=ktile*2+half) of 512 elem; lane(quad,l15) 16B =
// K[key=kt*64+ktile*16+l15][dh=half*32+quad*8 .. +7]
__device__ __forceinline__ size_t kpack(int bh, int key, int dh) {
    int kt = key >> 6, ktile = (key >> 4) & 3, kl = key & 15;
    int half = dh >> 5, qd = (dh >> 3) & 3, e = dh & 7;
    return ((size_t)((bh * 32 + kt) * 8 + ktile * 2 + half) * 512)
         + (qd * 16 + kl) * 8 + e;
}
// V frag-packed: chunk (kt, c=n*2+t) of 512 elem; lane(quad,l15) 16B =
// V[key=kt*64+(2t)*16+quad*4..+3][dh=n*16+l15] ++ same for ktile=2t+1
__device__ __forceinline__ size_t vpack(int bh, int key, int dh) {
    int kt = key >> 6, ktile = (key >> 4) & 3;
    int qd = (key >> 2) & 3, j = key & 3;
    int n = dh >> 4, l15 = dh & 15;
    return ((size_t)((bh * 32 + kt) * 8 + n * 2 + (ktile >> 1)) * 512)
         + (qd * 16 + l15) * 8 + (ktile & 1) * 4 + j;
}

// ---------------------------------------------------------------------------
// Prep (single launch): blocks [0,2048): x fp32->fp16 (+mask vec in block 0);
// blocks [2048, 5120): W transpose+convert -> Wt[z] (fp16 [N][K]).
// ---------------------------------------------------------------------------
__global__ __launch_bounds__(256) void prep_kernel(
    const float* __restrict__ x, unsigned short* __restrict__ xf,
    const int* __restrict__ mask, unsigned short* __restrict__ mb,
    const float* __restrict__ Wq, const float* __restrict__ Wk,
    const float* __restrict__ Wv, unsigned short* __restrict__ wt)
{
    __shared__ float tile[32][33];
    const int tid = threadIdx.x;

    if (blockIdx.x < 2048) {
        const size_t idx8 = ((size_t)blockIdx.x * 256 + tid) * 8;
        float4 v0 = *(const float4*)(x + idx8);
        float4 v1 = *(const float4*)(x + idx8 + 4);
        float f[8] = {v0.x, v0.y, v0.z, v0.w, v1.x, v1.y, v1.z, v1.w};
        unsigned short h[8];
#pragma unroll
        for (int i = 0; i < 8; i++) h[i] = f2h(f[i]);
        *(uint4*)(xf + idx8) = *(const uint4*)h;

        if (blockIdx.x == 0) {
#pragma unroll
            for (int j = 0; j < 16; j++) {
                int i = tid * 16 + j;               // covers B_*T_ = 4096
                mb[i] = (mask[i] != 0) ? (unsigned short)0x3C00 : (unsigned short)0;
            }
        }
    } else {
        const int idx = blockIdx.x - 2048;
        const int z   = idx >> 10;
        const int rem = idx & 1023;
        const int n0  = (rem & 31) * 32;
        const int k0  = (rem >> 5) * 32;
        const float* __restrict__ W = (z == 0) ? Wq : (z == 1) ? Wk : Wv;
        unsigned short* __restrict__ wtz = wt + (size_t)z * C_ * C_;
        const int tx = tid & 31;
        const int ty = tid >> 5;                    // 0..7
#pragma unroll
        for (int j = 0; j < 4; j++)
            tile[ty + j * 8][tx] = W[(size_t)(k0 + ty + j * 8) * C_ + n0 + tx];
        __syncthreads();
#pragma unroll
        for (int j = 0; j < 4; j++)
            wtz[(size_t)(n0 + ty + j * 8) * C_ + k0 + tx] = f2h(tile[tx][ty + j * 8]);
    }
}

// ---------------------------------------------------------------------------
// QKV projection (R12 main loop). z-grid, 3 blocks/CU. Q pre-scaled; K and V
// epilogues scatter into frag-packed layouts (kpack/vpack); V mask-zeroed.
// ---------------------------------------------------------------------------
__global__ __launch_bounds__(256) void qkv_mfma_kernel(
    const unsigned short* __restrict__ xf, const unsigned short* __restrict__ wt,
    const float* __restrict__ bq, const float* __restrict__ bk,
    const float* __restrict__ bv, const int* __restrict__ maskp,
    unsigned short* __restrict__ qb, unsigned short* __restrict__ kfr,
    unsigned short* __restrict__ vfr)
{
    __shared__ unsigned short sX[128 * 64];
    __shared__ unsigned short sW[128 * 64];

    const int z = blockIdx.z;
    const float* __restrict__ bias = (z == 0) ? bq : (z == 1) ? bk : bv;
    const unsigned short* __restrict__ wtz = wt + (size_t)z * C_ * C_;

    const int tok0 = blockIdx.x * 128;
    const int col0 = blockIdx.y * 128;
    const int wv    = threadIdx.x >> 6;
    const int lane  = threadIdx.x & 63;
    const int l15   = lane & 15;
    const int quad  = lane >> 4;
    const int l7    = l15 & 7;
    const int wm    = wv >> 1;
    const int wn    = wv & 1;
    const int lrow8 = lane >> 3;
    const int gch   = (lane & 7) ^ lrow8;

    f32x4 acc[4][4];
#pragma unroll
    for (int i = 0; i < 4; i++)
#pragma unroll
        for (int j = 0; j < 4; j++) acc[i][j] = (f32x4){0.f, 0.f, 0.f, 0.f};

    int aoff[4][2], boff[4][2];
#pragma unroll
    for (int i = 0; i < 4; i++)
#pragma unroll
        for (int s = 0; s < 2; s++) {
            aoff[i][s] = (wm * 64 + i * 16 + l15) * 64 + (((s * 4 + quad) ^ l7) * 8);
            boff[i][s] = (wn * 64 + i * 16 + l15) * 64 + (((s * 4 + quad) ^ l7) * 8);
        }

    const unsigned short* Abuf = (z < 2) ? sX : sW;
    const unsigned short* Bbuf = (z < 2) ? sW : sX;

    for (int k0 = 0; k0 < C_; k0 += 64) {
        __syncthreads();
#pragma unroll
        for (int s = 0; s < 8; ++s) {
            int g    = (s << 2) + wv;
            int tsel = g >> 4;
            int r0   = (g & 15) << 3;
            const unsigned short* src = tsel ? wtz : xf;
            unsigned short*       dst = tsel ? sW  : sX;
            int rowg = tsel ? col0 : tok0;
            gll16(src + (size_t)(rowg + r0 + lrow8) * C_ + k0 + gch * 8,
                  dst + r0 * 64);
        }
        __syncthreads();

        half8 af[4][2], bf_[4][2];
#pragma unroll
        for (int i = 0; i < 4; i++)
#pragma unroll
            for (int s = 0; s < 2; s++) {
                af[i][s]  = *(const half8*)&Abuf[aoff[i][s]];
                bf_[i][s] = *(const half8*)&Bbuf[boff[i][s]];
            }
#pragma unroll
        for (int s = 0; s < 2; s++)
#pragma unroll
            for (int j = 0; j < 4; j++)
#pragma unroll
                for (int i = 0; i < 4; i++)
                    acc[i][j] = __builtin_amdgcn_mfma_f32_16x16x32_f16(
                        af[i][s], bf_[j][s], acc[i][j], 0, 0, 0);
    }

    if (z == 0) {
#pragma unroll
        for (int j = 0; j < 4; j++) {
            int col = col0 + wn * 64 + j * 16 + l15;
            int h = col >> 6, d = col & 63;
            float bs = bias[col];
#pragma unroll
            for (int i = 0; i < 4; i++) {
#pragma unroll
                for (int r = 0; r < 4; r++) {
                    int tok = tok0 + wm * 64 + i * 16 + quad * 4 + r;
                    int bidx = tok >> 11, t = tok & (T_ - 1);
                    qb[((size_t)(bidx * H_ + h) * T_ + t) * DH_ + d] =
                        f2h((acc[i][j][r] + bs) * 0.18033688011112042f);
                }
            }
        }
    } else if (z == 1) {
#pragma unroll
        for (int j = 0; j < 4; j++) {
            int col = col0 + wn * 64 + j * 16 + l15;
            int h = col >> 6, d = col & 63;
            float bs = bias[col];
#pragma unroll
            for (int i = 0; i < 4; i++) {
#pragma unroll
                for (int r = 0; r < 4; r++) {
                    int tok = tok0 + wm * 64 + i * 16 + quad * 4 + r;
                    int bidx = tok >> 11, t = tok & (T_ - 1);
                    kfr[kpack(bidx * H_ + h, t, d)] = f2h(acc[i][j][r] + bs);
                }
            }
        }
    } else {
        float mv4[4]; int bidx4[4], t4[4];
#pragma unroll
        for (int j = 0; j < 4; j++) {
            int tok = tok0 + wn * 64 + j * 16 + l15;
            bidx4[j] = tok >> 11; t4[j] = tok & (T_ - 1);
            mv4[j] = (maskp[bidx4[j] * T_ + t4[j]] != 0) ? 1.f : 0.f;
        }
#pragma unroll
        for (int i = 0; i < 4; i++) {
#pragma unroll
            for (int r = 0; r < 4; r++) {
                int col = col0 + wm * 64 + i * 16 + quad * 4 + r;
                int h = col >> 6, d = col & 63;
                float bs = bias[col];
#pragma unroll
                for (int j = 0; j < 4; j++) {
                    vfr[vpack(bidx4[j] * H_ + h, t4[j], d)] =
                        f2h((acc[i][j][r] + bs) * mv4[j]);
                }
            }
        }
    }
}

// ---------------------------------------------------------------------------
// Attention R16: register-only P (R14) + frag-packed K/V LDS. All staging is
// linear 1KB chunks; all LDS reads are b128 at chunk*1024B + lane*16B (2-way
// max, conflict-free; zero address math). V half4 B-frags sliced in-register.
// ---------------------------------------------------------------------------
__global__ __launch_bounds__(256) void attn_mfma_kernel(
    const unsigned short* __restrict__ qb,  // [32][2048][64] f16 (pre-scaled)
    const unsigned short* __restrict__ kfr, // frag-packed K
    const unsigned short* __restrict__ vfr, // frag-packed V (mask-zeroed)
    const int* __restrict__ mask,           // [2][2048]
    const unsigned short* __restrict__ mb,  // [2][2048] f16 {0,1}
    float* __restrict__ out)                // [2][2048][1024]
{
    __shared__ unsigned short Ks[2][8 * 512];
    __shared__ unsigned short Vs[2][8 * 512];

    const int bh   = blockIdx.x;            // bh-major: same head -> same XCD
    const int b    = bh >> 4;
    const int h    = bh & 15;
    const int wv   = threadIdx.x >> 6;
    const int lane = threadIdx.x & 63;
    const int l15  = lane & 15;
    const int quad = lane >> 4;
    const int q0w  = blockIdx.y * 128 + wv * 32;

    const unsigned short* kfp = kfr + (size_t)bh * 131072;  // 32 kt x 8 x 512
    const unsigned short* vfp = vfr + (size_t)bh * 131072;
    const unsigned short* mbb = mb + b * T_;
    const int* __restrict__ mrow = mask + b * T_;

    half8 qf[2][2];
#pragma unroll
    for (int qt = 0; qt < 2; ++qt)
#pragma unroll
        for (int c = 0; c < 2; ++c)
            qf[qt][c] = *(const half8*)(qb + ((size_t)bh * T_ + q0w + qt * 16 + l15) * DH_
                                        + c * 32 + quad * 8);

    f32x4 o[2][4];
#pragma unroll
    for (int qt = 0; qt < 2; ++qt)
#pragma unroll
        for (int n = 0; n < 4; ++n) o[qt][n] = (f32x4){0.f, 0.f, 0.f, 0.f};
    f32x4 lacc[2];
    lacc[0] = (f32x4){0.f, 0.f, 0.f, 0.f};
    lacc[1] = (f32x4){0.f, 0.f, 0.f, 0.f};

    // prologue: stage tile 0 (wave wv takes chunks wv*4..wv*4+3 of 16)
#pragma unroll
    for (int s = 0; s < 4; ++s) {
        int c = (wv << 2) + s;
        if (c < 8) gll16(kfp + (size_t)c * 512 + lane * 8, &Ks[0][c * 512]);
        else       gll16(vfp + (size_t)(c - 8) * 512 + lane * 8, &Vs[0][(c - 8) * 512]);
    }

    for (int kt = 0; kt < 32; ++kt) {
        const int cur   = kt & 1;
        const int kbase = kt * 64;
        __syncthreads();

        if (kt < 31) {
            const size_t nb = (size_t)(kt + 1) * 4096;
#pragma unroll
            for (int s = 0; s < 4; ++s) {
                int c = (wv << 2) + s;
                if (c < 8) gll16(kfp + nb + (size_t)c * 512 + lane * 8,
                                 &Ks[cur ^ 1][c * 512]);
                else       gll16(vfp + nb + (size_t)(c - 8) * 512 + lane * 8,
                                 &Vs[cur ^ 1][(c - 8) * 512]);
            }
        }

        const unsigned short* Kc = &Ks[cur][0];
        const unsigned short* Vc = &Vs[cur][0];

        // K A-frags (16x16x32): chunk ktile*2+half, b128 at lane*16B
        half8 kf[4][2];
#pragma unroll
        for (int c = 0; c < 8; ++c)
            kf[c >> 1][c & 1] = *(const half8*)(Kc + c * 512 + lane * 8);

        // V frags: chunk n*2+t holds ktile=2t (lo half4) and 2t+1 (hi half4)
        half8 vv[4][2];
#pragma unroll
        for (int c = 0; c < 8; ++c)
            vv[c >> 1][c & 1] = *(const half8*)(Vc + c * 512 + lane * 8);

        // mask B-frags (16x16x16, col n=0): keys ktile*16+quad*4..+3
        half4 bmf[4];
#pragma unroll
        for (int ktile = 0; ktile < 4; ++ktile) {
            half4 mv = *(const half4*)(mbb + kbase + ktile * 16 + quad * 4);
            bmf[ktile] = (l15 == 0) ? mv : (half4)0;
        }

#pragma unroll
        for (int qt = 0; qt < 2; ++qt) {
            // S^T -> exp -> in-register A-frags (half4 per ktile)
            half4 pa[4];
#pragma unroll
            for (int ktile = 0; ktile < 4; ++ktile) {
                f32x4 st = (f32x4){0.f, 0.f, 0.f, 0.f};
                st = __builtin_amdgcn_mfma_f32_16x16x32_f16(kf[ktile][0], qf[qt][0], st, 0, 0, 0);
                st = __builtin_amdgcn_mfma_f32_16x16x32_f16(kf[ktile][1], qf[qt][1], st, 0, 0, 0);
                union { uint2 u; half4 h; } cv;
                cv.u.x = pk2(__builtin_amdgcn_exp2f(st[0]), __builtin_amdgcn_exp2f(st[1]));
                cv.u.y = pk2(__builtin_amdgcn_exp2f(st[2]), __builtin_amdgcn_exp2f(st[3]));
                pa[ktile] = cv.h;
            }

            // l += P . maskvec
#pragma unroll
            for (int ktile = 0; ktile < 4; ++ktile)
                lacc[qt] = __builtin_amdgcn_mfma_f32_16x16x16f16(
                    pa[ktile], bmf[ktile], lacc[qt], 0, 0, 0);

            // O += P V (vb = half4 slice of vv[n][ktile>>1])
#pragma unroll
            for (int n = 0; n < 4; ++n) {
#pragma unroll
                for (int t = 0; t < 2; ++t) {
                    half4 vlo = __builtin_shufflevector(vv[n][t], vv[n][t], 0, 1, 2, 3);
                    half4 vhi = __builtin_shufflevector(vv[n][t], vv[n][t], 4, 5, 6, 7);
                    o[qt][n] = __builtin_amdgcn_mfma_f32_16x16x16f16(
                        pa[t * 2], vlo, o[qt][n], 0, 0, 0);
                    o[qt][n] = __builtin_amdgcn_mfma_f32_16x16x16f16(
                        pa[t * 2 + 1], vhi, o[qt][n], 0, 0, 0);
                }
            }
        }
    }

#pragma unroll
    for (int qt = 0; qt < 2; ++qt) {
#pragma unroll
        for (int r = 0; r < 4; ++r) {
            float lv = __shfl(lacc[qt][r], quad << 4, 64);
            int q = q0w + qt * 16 + quad * 4 + r;
            float iv = (mrow[q] != 0 && lv > 0.f) ? (1.0f / lv) : 0.f;
            float* orow = out + ((size_t)(b * T_ + q)) * C_ + h * DH_;
#pragma unroll
            for (int n = 0; n < 4; ++n)
                orow[n * 16 + l15] = o[qt][n][r] * iv;
        }
    }
}

// ---------------------------------------------------------------------------
extern "C" void kernel_launch(void* const* d_in, const int* in_sizes, int n_in,
                              void* d_out, int out_size, void* d_ws, size_t ws_size,
                              hipStream_t stream)
{
    (void)in_sizes; (void)n_in; (void)out_size; (void)ws_size;
    const float* x  = (const float*)d_in[0];
    const float* Wq = (const float*)d_in[1];
    const float* bq = (const float*)d_in[2];
    const float* Wk = (const float*)d_in[3];
    const float* bk = (const float*)d_in[4];
    const float* Wv = (const float*)d_in[5];
    const float* bv = (const float*)d_in[6];
    const int* mask = (const int*)d_in[7];
    float* out = (float*)d_out;

    const size_t NX = (size_t)B_ * T_ * C_;          // 4 Mi elements
    unsigned short* xf  = (unsigned short*)d_ws;      // 8 MB fp16 x
    unsigned short* wt  = xf + NX;                    // 6 MB fp16 W^T x3
    unsigned short* qb  = wt + (size_t)3 * C_ * C_;   // 8 MB (pre-scaled q)
    unsigned short* kfr = qb + NX;                    // 8 MB frag-packed K
    unsigned short* vfr = kfr + NX;                   // 8 MB frag-packed V
    unsigned short* mb  = vfr + NX;                   // 8 KB

    prep_kernel<<<5120, 256, 0, stream>>>(x, xf, mask, mb, Wq, Wk, Wv, wt);
    qkv_mfma_kernel<<<dim3(32, 8, 3), 256, 0, stream>>>(
        xf, wt, bq, bk, bv, mask, qb, kfr, vfr);
    attn_mfma_kernel<<<dim3(32, 16), 256, 0, stream>>>(qb, kfr, vfr, mask, mb, out);
}

// Round 17
// 176.248 us; speedup vs baseline: 1.0358x; 1.0358x over previous
//
#include <hip/hip_runtime.h>

#define B_ 2
#define T_ 2048
#define C_ 1024
#define H_ 16
#define DH_ 64

typedef __attribute__((ext_vector_type(8))) _Float16 half8;  // 8 f16 (4 VGPRs)
typedef __attribute__((ext_vector_type(4))) _Float16 half4;  // 4 f16 (2 VGPRs)
typedef __attribute__((ext_vector_type(2))) __fp16 fp16x2;   // cvt_pkrtz result type
typedef __attribute__((ext_vector_type(4))) float f32x4;

__device__ __forceinline__ unsigned short f2h(float f) {
    union { _Float16 h; unsigned short u; } cv; cv.h = (_Float16)f; return cv.u;
}
__device__ __forceinline__ unsigned pk2(float a, float b) {
    union { fp16x2 h; unsigned u; } cv;
    cv.h = __builtin_amdgcn_cvt_pkrtz(a, b);
    return cv.u;
}

__device__ __forceinline__ void gll16(const void* g, void* l) {
    __builtin_amdgcn_global_load_lds(
        (const __attribute__((address_space(1))) void*)g,
        (__attribute__((address_space(3))) void*)l, 16, 0, 0);
}

// ---------------------------------------------------------------------------
// Prep (single launch): blocks [0,2048): x fp32->fp16 (+mask vec in block 0);
// blocks [2048, 5120): W transpose+convert -> Wt[z] (fp16 [N][K]).
// ---------------------------------------------------------------------------
__global__ __launch_bounds__(256) void prep_kernel(
    const float* __restrict__ x, unsigned short* __restrict__ xf,
    const int* __restrict__ mask, unsigned short* __restrict__ mb,
    const float* __restrict__ Wq, const float* __restrict__ Wk,
    const float* __restrict__ Wv, unsigned short* __restrict__ wt)
{
    __shared__ float tile[32][33];
    const int tid = threadIdx.x;

    if (blockIdx.x < 2048) {
        const size_t idx8 = ((size_t)blockIdx.x * 256 + tid) * 8;
        float4 v0 = *(const float4*)(x + idx8);
        float4 v1 = *(const float4*)(x + idx8 + 4);
        float f[8] = {v0.x, v0.y, v0.z, v0.w, v1.x, v1.y, v1.z, v1.w};
        unsigned short h[8];
#pragma unroll
        for (int i = 0; i < 8; i++) h[i] = f2h(f[i]);
        *(uint4*)(xf + idx8) = *(const uint4*)h;

        if (blockIdx.x == 0) {
#pragma unroll
            for (int j = 0; j < 16; j++) {
                int i = tid * 16 + j;               // covers B_*T_ = 4096
                mb[i] = (mask[i] != 0) ? (unsigned short)0x3C00 : (unsigned short)0;
            }
        }
    } else {
        const int idx = blockIdx.x - 2048;
        const int z   = idx >> 10;
        const int rem = idx & 1023;
        const int n0  = (rem & 31) * 32;
        const int k0  = (rem >> 5) * 32;
        const float* __restrict__ W = (z == 0) ? Wq : (z == 1) ? Wk : Wv;
        unsigned short* __restrict__ wtz = wt + (size_t)z * C_ * C_;
        const int tx = tid & 31;
        const int ty = tid >> 5;                    // 0..7
#pragma unroll
        for (int j = 0; j < 4; j++)
            tile[ty + j * 8][tx] = W[(size_t)(k0 + ty + j * 8) * C_ + n0 + tx];
        __syncthreads();
#pragma unroll
        for (int j = 0; j < 4; j++)
            wtz[(size_t)(n0 + ty + j * 8) * C_ + k0 + tx] = f2h(tile[tx][ty + j * 8]);
    }
}

// ---------------------------------------------------------------------------
// QKV projection R17: z=0 computes q AND k for its tile (X staged ONCE,
// shared A-fragments, 48 KB LDS, 64 MFMA : 24 ds_read per wave-iter);
// z=1 is the v path (operand swap -> transposed output). Grid 512 = 2/CU.
// Q pre-scaled by log2(e)/8; V mask-zeroed.
// ---------------------------------------------------------------------------
__global__ __launch_bounds__(256) void qkv_mfma_kernel(
    const unsigned short* __restrict__ xf, const unsigned short* __restrict__ wt,
    const float* __restrict__ bq, const float* __restrict__ bk,
    const float* __restrict__ bv, const int* __restrict__ maskp,
    unsigned short* __restrict__ qb, unsigned short* __restrict__ kb,
    unsigned short* __restrict__ vt)
{
    __shared__ unsigned short sX [128 * 64];   // 16 KB
    __shared__ unsigned short sW0[128 * 64];   // 16 KB (Wq or Wv)
    __shared__ unsigned short sW1[128 * 64];   // 16 KB (Wk; unused for z=1)

    const int z = blockIdx.z;                  // 0: q+k fused, 1: v

    const int tok0 = blockIdx.x * 128;
    const int col0 = blockIdx.y * 128;
    const int wv    = threadIdx.x >> 6;
    const int lane  = threadIdx.x & 63;
    const int l15   = lane & 15;
    const int quad  = lane >> 4;
    const int l7    = l15 & 7;
    const int wm    = wv >> 1;
    const int wn    = wv & 1;
    const int lrow8 = lane >> 3;
    const int gch   = (lane & 7) ^ lrow8;

    int aoff[4][2], boff[4][2];
#pragma unroll
    for (int i = 0; i < 4; i++)
#pragma unroll
        for (int s = 0; s < 2; s++) {
            aoff[i][s] = (wm * 64 + i * 16 + l15) * 64 + (((s * 4 + quad) ^ l7) * 8);
            boff[i][s] = (wn * 64 + i * 16 + l15) * 64 + (((s * 4 + quad) ^ l7) * 8);
        }

    if (z == 0) {
        // ---------------- q + k fused ----------------
        const unsigned short* wq = wt;                        // Wt[0]
        const unsigned short* wk = wt + (size_t)C_ * C_;      // Wt[1]

        f32x4 accq[4][4], acck[4][4];
#pragma unroll
        for (int i = 0; i < 4; i++)
#pragma unroll
            for (int j = 0; j < 4; j++) {
                accq[i][j] = (f32x4){0.f, 0.f, 0.f, 0.f};
                acck[i][j] = (f32x4){0.f, 0.f, 0.f, 0.f};
            }

        for (int k0 = 0; k0 < C_; k0 += 64) {
            __syncthreads();
            // stage 48 groups of (8 rows x 128 B): X 0..15, Wq 16..31, Wk 32..47
#pragma unroll
            for (int s = 0; s < 12; ++s) {
                int g = (s << 2) + wv;
                const unsigned short* src;
                unsigned short* dst;
                int rowg, r0;
                if (g < 16)      { src = xf; dst = sX;  rowg = tok0; r0 = g << 3; }
                else if (g < 32) { src = wq; dst = sW0; rowg = col0; r0 = (g - 16) << 3; }
                else             { src = wk; dst = sW1; rowg = col0; r0 = (g - 32) << 3; }
                gll16(src + (size_t)(rowg + r0 + lrow8) * C_ + k0 + gch * 8,
                      dst + r0 * 64);
            }
            __syncthreads();

            half8 af[4][2];
#pragma unroll
            for (int i = 0; i < 4; i++)
#pragma unroll
                for (int s = 0; s < 2; s++)
                    af[i][s] = *(const half8*)&sX[aoff[i][s]];

#pragma unroll
            for (int j = 0; j < 4; j++) {
                half8 bq0 = *(const half8*)&sW0[boff[j][0]];
                half8 bq1 = *(const half8*)&sW0[boff[j][1]];
                half8 bk0 = *(const half8*)&sW1[boff[j][0]];
                half8 bk1 = *(const half8*)&sW1[boff[j][1]];
#pragma unroll
                for (int i = 0; i < 4; i++) {
                    accq[i][j] = __builtin_amdgcn_mfma_f32_16x16x32_f16(af[i][0], bq0, accq[i][j], 0, 0, 0);
                    accq[i][j] = __builtin_amdgcn_mfma_f32_16x16x32_f16(af[i][1], bq1, accq[i][j], 0, 0, 0);
                    acck[i][j] = __builtin_amdgcn_mfma_f32_16x16x32_f16(af[i][0], bk0, acck[i][j], 0, 0, 0);
                    acck[i][j] = __builtin_amdgcn_mfma_f32_16x16x32_f16(af[i][1], bk1, acck[i][j], 0, 0, 0);
                }
            }
        }

        // epilogue: q (scaled) and k, contiguous [bh][T][64]
#pragma unroll
        for (int j = 0; j < 4; j++) {
            int col = col0 + wn * 64 + j * 16 + l15;
            int h = col >> 6, d = col & 63;
            float bsq = bq[col];
            float bsk = bk[col];
#pragma unroll
            for (int i = 0; i < 4; i++) {
#pragma unroll
                for (int r = 0; r < 4; r++) {
                    int tok = tok0 + wm * 64 + i * 16 + quad * 4 + r;
                    int bidx = tok >> 11, t = tok & (T_ - 1);
                    size_t base = ((size_t)(bidx * H_ + h) * T_ + t) * DH_ + d;
                    qb[base] = f2h((accq[i][j][r] + bsq) * 0.18033688011112042f);
                    kb[base] = f2h(acck[i][j][r] + bsk);
                }
            }
        }
    } else {
        // ---------------- v (operand swap -> transposed out) ----------------
        const unsigned short* wv_ = wt + (size_t)2 * C_ * C_; // Wt[2]

        f32x4 acc[4][4];
#pragma unroll
        for (int i = 0; i < 4; i++)
#pragma unroll
            for (int j = 0; j < 4; j++) acc[i][j] = (f32x4){0.f, 0.f, 0.f, 0.f};

        for (int k0 = 0; k0 < C_; k0 += 64) {
            __syncthreads();
            // stage 32 groups: X 0..15 -> sX, Wv 16..31 -> sW0
#pragma unroll
            for (int s = 0; s < 8; ++s) {
                int g = (s << 2) + wv;
                const unsigned short* src = (g < 16) ? xf : wv_;
                unsigned short*       dst = (g < 16) ? sX : sW0;
                int rowg = (g < 16) ? tok0 : col0;
                int r0   = (g & 15) << 3;
                gll16(src + (size_t)(rowg + r0 + lrow8) * C_ + k0 + gch * 8,
                      dst + r0 * 64);
            }
            __syncthreads();

            half8 aw[4][2], bf_[4][2];
#pragma unroll
            for (int i = 0; i < 4; i++)
#pragma unroll
                for (int s = 0; s < 2; s++) {
                    aw[i][s]  = *(const half8*)&sW0[aoff[i][s]];
                    bf_[i][s] = *(const half8*)&sX[boff[i][s]];
                }
#pragma unroll
            for (int s = 0; s < 2; s++)
#pragma unroll
                for (int j = 0; j < 4; j++)
#pragma unroll
                    for (int i = 0; i < 4; i++)
                        acc[i][j] = __builtin_amdgcn_mfma_f32_16x16x32_f16(
                            aw[i][s], bf_[j][s], acc[i][j], 0, 0, 0);
        }

        float mv4[4]; int bidx4[4], t4[4];
#pragma unroll
        for (int j = 0; j < 4; j++) {
            int tok = tok0 + wn * 64 + j * 16 + l15;
            bidx4[j] = tok >> 11; t4[j] = tok & (T_ - 1);
            mv4[j] = (maskp[bidx4[j] * T_ + t4[j]] != 0) ? 1.f : 0.f;
        }
#pragma unroll
        for (int i = 0; i < 4; i++) {
#pragma unroll
            for (int r = 0; r < 4; r++) {
                int col = col0 + wm * 64 + i * 16 + quad * 4 + r;
                int h = col >> 6, d = col & 63;
                float bs = bv[col];
#pragma unroll
                for (int j = 0; j < 4; j++) {
                    vt[((size_t)(bidx4[j] * H_ + h) * DH_ + d) * T_ + t4[j]] =
                        f2h((acc[i][j][r] + bs) * mv4[j]);
                }
            }
        }
    }
}

// ---------------------------------------------------------------------------
// Attention: R14 verbatim (best measured config — register-only P path,
// XOR-swizzled K/V LDS double-buffer, bh-major grid; the 4-way V b64
// conflicts are accepted: R16 proved eliminating them costs more than it saves).
// ---------------------------------------------------------------------------
__global__ __launch_bounds__(256) void attn_mfma_kernel(
    const unsigned short* __restrict__ qb,  // [32][2048][64] f16 (pre-scaled)
    const unsigned short* __restrict__ kb,  // [32][2048][64] f16
    const unsigned short* __restrict__ vt,  // [32][64][2048] f16 (mask-zeroed)
    const int* __restrict__ mask,           // [2][2048]
    const unsigned short* __restrict__ mb,  // [2][2048] f16 {0,1}
    float* __restrict__ out)                // [2][2048][1024]
{
    __shared__ unsigned short Ks[2][64 * 64];
    __shared__ unsigned short Vs[2][64 * 64];

    const int bh   = blockIdx.x;            // bh-major: same head -> same XCD
    const int b    = bh >> 4;
    const int h    = bh & 15;
    const int wv   = threadIdx.x >> 6;
    const int lane = threadIdx.x & 63;
    const int l15  = lane & 15;
    const int quad = lane >> 4;
    const int l7   = l15 & 7;
    const int q0w  = blockIdx.y * 128 + wv * 32;

    const unsigned short* kbh = kb + (size_t)bh * T_ * DH_;
    const unsigned short* vbh = vt + (size_t)bh * DH_ * T_;
    const unsigned short* mbb = mb + b * T_;
    const int* __restrict__ mrow = mask + b * T_;

    half8 qf[2][2];
#pragma unroll
    for (int qt = 0; qt < 2; ++qt)
#pragma unroll
        for (int c = 0; c < 2; ++c)
            qf[qt][c] = *(const half8*)(qb + ((size_t)bh * T_ + q0w + qt * 16 + l15) * DH_
                                        + c * 32 + quad * 8);

    f32x4 o[2][4];
#pragma unroll
    for (int qt = 0; qt < 2; ++qt)
#pragma unroll
        for (int n = 0; n < 4; ++n) o[qt][n] = (f32x4){0.f, 0.f, 0.f, 0.f};
    f32x4 lacc[2];
    lacc[0] = (f32x4){0.f, 0.f, 0.f, 0.f};
    lacc[1] = (f32x4){0.f, 0.f, 0.f, 0.f};

    const int lrow = lane >> 3;
    const int gch  = (lane & 7) ^ lrow;

#pragma unroll
    for (int s = 0; s < 4; ++s) {
        int j  = (wv << 2) + s;
        int rb = j & 7;
        if (j < 8) gll16(kbh + (size_t)(rb * 8 + lrow) * DH_ + gch * 8, &Ks[0][rb * 512]);
        else       gll16(vbh + (size_t)(rb * 8 + lrow) * T_  + gch * 8, &Vs[0][rb * 512]);
    }

    for (int kt = 0; kt < 32; ++kt) {
        const int cur   = kt & 1;
        const int kbase = kt * 64;
        __syncthreads();

        if (kt < 31) {
            const int nb = kbase + 64;
#pragma unroll
            for (int s = 0; s < 4; ++s) {
                int j  = (wv << 2) + s;
                int rb = j & 7;
                if (j < 8) gll16(kbh + (size_t)(nb + rb * 8 + lrow) * DH_ + gch * 8,
                                 &Ks[cur ^ 1][rb * 512]);
                else       gll16(vbh + (size_t)(rb * 8 + lrow) * T_ + nb + gch * 8,
                                 &Vs[cur ^ 1][rb * 512]);
            }
        }

        const unsigned short* Kc = &Ks[cur][0];
        const unsigned short* Vc = &Vs[cur][0];

        // K A-frags (16x16x32): K[ktile*16+l15][c*32+quad*8..]
        half8 kf[4][2];
#pragma unroll
        for (int ktile = 0; ktile < 4; ++ktile)
#pragma unroll
            for (int c = 0; c < 2; ++c)
                kf[ktile][c] = *(const half8*)(Kc + (ktile * 16 + l15) * 64
                                               + (((c * 4 + quad) ^ l7) * 8));

        // V B-frags (16x16x16): B[k=quad*4+j][n=l15]
        half4 vb[4][4];   // [n][ktile]
#pragma unroll
        for (int n = 0; n < 4; ++n)
#pragma unroll
            for (int ktile = 0; ktile < 4; ++ktile)
                vb[n][ktile] = *(const half4*)(Vc + (n * 16 + l15) * 64
                                               + (((ktile * 2 + (quad >> 1)) ^ l7) * 8)
                                               + (quad & 1) * 4);

        // mask B-frags (16x16x16, col n=0): keys ktile*16+quad*4..+3
        half4 bmf[4];
#pragma unroll
        for (int ktile = 0; ktile < 4; ++ktile) {
            half4 mv = *(const half4*)(mbb + kbase + ktile * 16 + quad * 4);
            bmf[ktile] = (l15 == 0) ? mv : (half4)0;
        }

#pragma unroll
        for (int qt = 0; qt < 2; ++qt) {
            // S^T -> exp -> in-register A-frags (half4 per ktile)
            half4 pa[4];
#pragma unroll
            for (int ktile = 0; ktile < 4; ++ktile) {
                f32x4 st = (f32x4){0.f, 0.f, 0.f, 0.f};
                st = __builtin_amdgcn_mfma_f32_16x16x32_f16(kf[ktile][0], qf[qt][0], st, 0, 0, 0);
                st = __builtin_amdgcn_mfma_f32_16x16x32_f16(kf[ktile][1], qf[qt][1], st, 0, 0, 0);
                union { uint2 u; half4 h; } cv;
                cv.u.x = pk2(__builtin_amdgcn_exp2f(st[0]), __builtin_amdgcn_exp2f(st[1]));
                cv.u.y = pk2(__builtin_amdgcn_exp2f(st[2]), __builtin_amdgcn_exp2f(st[3]));
                pa[ktile] = cv.h;
            }

            // l += P . maskvec
#pragma unroll
            for (int ktile = 0; ktile < 4; ++ktile)
                lacc[qt] = __builtin_amdgcn_mfma_f32_16x16x16f16(
                    pa[ktile], bmf[ktile], lacc[qt], 0, 0, 0);

            // O += P V
#pragma unroll
            for (int n = 0; n < 4; ++n)
#pragma unroll
                for (int ktile = 0; ktile < 4; ++ktile)
                    o[qt][n] = __builtin_amdgcn_mfma_f32_16x16x16f16(
                        pa[ktile], vb[n][ktile], o[qt][n], 0, 0, 0);
        }
    }

#pragma unroll
    for (int qt = 0; qt < 2; ++qt) {
#pragma unroll
        for (int r = 0; r < 4; ++r) {
            float lv = __shfl(lacc[qt][r], quad << 4, 64);
            int q = q0w + qt * 16 + quad * 4 + r;
            float iv = (mrow[q] != 0 && lv > 0.f) ? (1.0f / lv) : 0.f;
            float* orow = out + ((size_t)(b * T_ + q)) * C_ + h * DH_;
#pragma unroll
            for (int n = 0; n < 4; ++n)
                orow[n * 16 + l15] = o[qt][n][r] * iv;
        }
    }
}

// ---------------------------------------------------------------------------
extern "C" void kernel_launch(void* const* d_in, const int* in_sizes, int n_in,
                              void* d_out, int out_size, void* d_ws, size_t ws_size,
                              hipStream_t stream)
{
    (void)in_sizes; (void)n_in; (void)out_size; (void)ws_size;
    const float* x  = (const float*)d_in[0];
    const float* Wq = (const float*)d_in[1];
    const float* bq = (const float*)d_in[2];
    const float* Wk = (const float*)d_in[3];
    const float* bk = (const float*)d_in[4];
    const float* Wv = (const float*)d_in[5];
    const float* bv = (const float*)d_in[6];
    const int* mask = (const int*)d_in[7];
    float* out = (float*)d_out;

    const size_t NX = (size_t)B_ * T_ * C_;          // 4 Mi elements
    unsigned short* xf = (unsigned short*)d_ws;       // 8 MB fp16 x
    unsigned short* wt = xf + NX;                     // 6 MB fp16 W^T x3
    unsigned short* qb = wt + (size_t)3 * C_ * C_;    // 8 MB (pre-scaled q)
    unsigned short* kb = qb + NX;                     // 8 MB
    unsigned short* vt = kb + NX;                     // 8 MB
    unsigned short* mb = vt + NX;                     // 8 KB

    prep_kernel<<<5120, 256, 0, stream>>>(x, xf, mask, mb, Wq, Wk, Wv, wt);
    qkv_mfma_kernel<<<dim3(32, 8, 2), 256, 0, stream>>>(
        xf, wt, bq, bk, bv, mask, qb, kb, vt);
    attn_mfma_kernel<<<dim3(32, 16), 256, 0, stream>>>(qb, kb, vt, mask, mb, out);
}

// Round 18
// 168.035 us; speedup vs baseline: 1.0865x; 1.0489x over previous
//
#include <hip/hip_runtime.h>

#define B_ 2
#define T_ 2048
#define C_ 1024
#define H_ 16
#define DH_ 64

typedef __attribute__((ext_vector_type(8))) _Float16 half8;  // 8 f16 (4 VGPRs)
typedef __attribute__((ext_vector_type(4))) _Float16 half4;  // 4 f16 (2 VGPRs)
typedef __attribute__((ext_vector_type(2))) __fp16 fp16x2;   // cvt_pkrtz result type
typedef __attribute__((ext_vector_type(4))) float f32x4;

__device__ __forceinline__ unsigned short f2h(float f) {
    union { _Float16 h; unsigned short u; } cv; cv.h = (_Float16)f; return cv.u;
}
__device__ __forceinline__ unsigned pk2(float a, float b) {
    union { fp16x2 h; unsigned u; } cv;
    cv.h = __builtin_amdgcn_cvt_pkrtz(a, b);
    return cv.u;
}

__device__ __forceinline__ void gll16(const void* g, void* l) {
    __builtin_amdgcn_global_load_lds(
        (const __attribute__((address_space(1))) void*)g,
        (__attribute__((address_space(3))) void*)l, 16, 0, 0);
}

// ---------------------------------------------------------------------------
// Prep (single launch): blocks [0,2048): x fp32->fp16 (+mask vec in block 0);
// blocks [2048, 5120): W transpose+convert -> Wt[z] (fp16 [N][K]).
// ---------------------------------------------------------------------------
__global__ __launch_bounds__(256) void prep_kernel(
    const float* __restrict__ x, unsigned short* __restrict__ xf,
    const int* __restrict__ mask, unsigned short* __restrict__ mb,
    const float* __restrict__ Wq, const float* __restrict__ Wk,
    const float* __restrict__ Wv, unsigned short* __restrict__ wt)
{
    __shared__ float tile[32][33];
    const int tid = threadIdx.x;

    if (blockIdx.x < 2048) {
        const size_t idx8 = ((size_t)blockIdx.x * 256 + tid) * 8;
        float4 v0 = *(const float4*)(x + idx8);
        float4 v1 = *(const float4*)(x + idx8 + 4);
        float f[8] = {v0.x, v0.y, v0.z, v0.w, v1.x, v1.y, v1.z, v1.w};
        unsigned short h[8];
#pragma unroll
        for (int i = 0; i < 8; i++) h[i] = f2h(f[i]);
        *(uint4*)(xf + idx8) = *(const uint4*)h;

        if (blockIdx.x == 0) {
#pragma unroll
            for (int j = 0; j < 16; j++) {
                int i = tid * 16 + j;               // covers B_*T_ = 4096
                mb[i] = (mask[i] != 0) ? (unsigned short)0x3C00 : (unsigned short)0;
            }
        }
    } else {
        const int idx = blockIdx.x - 2048;
        const int z   = idx >> 10;
        const int rem = idx & 1023;
        const int n0  = (rem & 31) * 32;
        const int k0  = (rem >> 5) * 32;
        const float* __restrict__ W = (z == 0) ? Wq : (z == 1) ? Wk : Wv;
        unsigned short* __restrict__ wtz = wt + (size_t)z * C_ * C_;
        const int tx = tid & 31;
        const int ty = tid >> 5;                    // 0..7
#pragma unroll
        for (int j = 0; j < 4; j++)
            tile[ty + j * 8][tx] = W[(size_t)(k0 + ty + j * 8) * C_ + n0 + tx];
        __syncthreads();
#pragma unroll
        for (int j = 0; j < 4; j++)
            wtz[(size_t)(n0 + ty + j * 8) * C_ + k0 + tx] = f2h(tile[tx][ty + j * 8]);
    }
}

// ---------------------------------------------------------------------------
// QKV projection (R12 structure — best measured). z-grid, 768 blocks = 3/CU,
// 32 KB LDS. Q pre-scaled by log2(e)/8; V transposed + mask-zeroed.
// ---------------------------------------------------------------------------
__global__ __launch_bounds__(256) void qkv_mfma_kernel(
    const unsigned short* __restrict__ xf, const unsigned short* __restrict__ wt,
    const float* __restrict__ bq, const float* __restrict__ bk,
    const float* __restrict__ bv, const int* __restrict__ maskp,
    unsigned short* __restrict__ qb, unsigned short* __restrict__ kb,
    unsigned short* __restrict__ vt)
{
    __shared__ unsigned short sX[128 * 64];
    __shared__ unsigned short sW[128 * 64];

    const int z = blockIdx.z;
    const float* __restrict__ bias = (z == 0) ? bq : (z == 1) ? bk : bv;
    const unsigned short* __restrict__ wtz = wt + (size_t)z * C_ * C_;

    const int tok0 = blockIdx.x * 128;
    const int col0 = blockIdx.y * 128;
    const int wv    = threadIdx.x >> 6;
    const int lane  = threadIdx.x & 63;
    const int l15   = lane & 15;
    const int quad  = lane >> 4;
    const int l7    = l15 & 7;
    const int wm    = wv >> 1;
    const int wn    = wv & 1;
    const int lrow8 = lane >> 3;
    const int gch   = (lane & 7) ^ lrow8;

    f32x4 acc[4][4];
#pragma unroll
    for (int i = 0; i < 4; i++)
#pragma unroll
        for (int j = 0; j < 4; j++) acc[i][j] = (f32x4){0.f, 0.f, 0.f, 0.f};

    int aoff[4][2], boff[4][2];
#pragma unroll
    for (int i = 0; i < 4; i++)
#pragma unroll
        for (int s = 0; s < 2; s++) {
            aoff[i][s] = (wm * 64 + i * 16 + l15) * 64 + (((s * 4 + quad) ^ l7) * 8);
            boff[i][s] = (wn * 64 + i * 16 + l15) * 64 + (((s * 4 + quad) ^ l7) * 8);
        }

    const unsigned short* Abuf = (z < 2) ? sX : sW;
    const unsigned short* Bbuf = (z < 2) ? sW : sX;

    for (int k0 = 0; k0 < C_; k0 += 64) {
        __syncthreads();
#pragma unroll
        for (int s = 0; s < 8; ++s) {
            int g    = (s << 2) + wv;
            int tsel = g >> 4;
            int r0   = (g & 15) << 3;
            const unsigned short* src = tsel ? wtz : xf;
            unsigned short*       dst = tsel ? sW  : sX;
            int rowg = tsel ? col0 : tok0;
            gll16(src + (size_t)(rowg + r0 + lrow8) * C_ + k0 + gch * 8,
                  dst + r0 * 64);
        }
        __syncthreads();

        half8 af[4][2], bf_[4][2];
#pragma unroll
        for (int i = 0; i < 4; i++)
#pragma unroll
            for (int s = 0; s < 2; s++) {
                af[i][s]  = *(const half8*)&Abuf[aoff[i][s]];
                bf_[i][s] = *(const half8*)&Bbuf[boff[i][s]];
            }
#pragma unroll
        for (int s = 0; s < 2; s++)
#pragma unroll
            for (int j = 0; j < 4; j++)
#pragma unroll
                for (int i = 0; i < 4; i++)
                    acc[i][j] = __builtin_amdgcn_mfma_f32_16x16x32_f16(
                        af[i][s], bf_[j][s], acc[i][j], 0, 0, 0);
    }

    if (z == 0) {
#pragma unroll
        for (int j = 0; j < 4; j++) {
            int col = col0 + wn * 64 + j * 16 + l15;
            int h = col >> 6, d = col & 63;
            float bs = bias[col];
#pragma unroll
            for (int i = 0; i < 4; i++) {
#pragma unroll
                for (int r = 0; r < 4; r++) {
                    int tok = tok0 + wm * 64 + i * 16 + quad * 4 + r;
                    int bidx = tok >> 11, t = tok & (T_ - 1);
                    qb[((size_t)(bidx * H_ + h) * T_ + t) * DH_ + d] =
                        f2h((acc[i][j][r] + bs) * 0.18033688011112042f);
                }
            }
        }
    } else if (z == 1) {
#pragma unroll
        for (int j = 0; j < 4; j++) {
            int col = col0 + wn * 64 + j * 16 + l15;
            int h = col >> 6, d = col & 63;
            float bs = bias[col];
#pragma unroll
            for (int i = 0; i < 4; i++) {
#pragma unroll
                for (int r = 0; r < 4; r++) {
                    int tok = tok0 + wm * 64 + i * 16 + quad * 4 + r;
                    int bidx = tok >> 11, t = tok & (T_ - 1);
                    kb[((size_t)(bidx * H_ + h) * T_ + t) * DH_ + d] =
                        f2h(acc[i][j][r] + bs);
                }
            }
        }
    } else {
        float mv4[4]; int bidx4[4], t4[4];
#pragma unroll
        for (int j = 0; j < 4; j++) {
            int tok = tok0 + wn * 64 + j * 16 + l15;
            bidx4[j] = tok >> 11; t4[j] = tok & (T_ - 1);
            mv4[j] = (maskp[bidx4[j] * T_ + t4[j]] != 0) ? 1.f : 0.f;
        }
#pragma unroll
        for (int i = 0; i < 4; i++) {
#pragma unroll
            for (int r = 0; r < 4; r++) {
                int col = col0 + wm * 64 + i * 16 + quad * 4 + r;
                int h = col >> 6, d = col & 63;
                float bs = bias[col];
#pragma unroll
                for (int j = 0; j < 4; j++) {
                    vt[((size_t)(bidx4[j] * H_ + h) * DH_ + d) * T_ + t4[j]] =
                        f2h((acc[i][j][r] + bs) * mv4[j]);
                }
            }
        }
    }
}

// ---------------------------------------------------------------------------
// Attention (R14 verbatim — best measured): register-only P path (S^T C-layout
// == 16x16x16 A-layout), XOR-swizzled K/V LDS double-buffer, bh-major grid.
// The 4-way V b64 conflicts are accepted (R16 proved removing them is a net
// loss); the kernel is dependency-latency bound, not pipe-bound.
// ---------------------------------------------------------------------------
__global__ __launch_bounds__(256) void attn_mfma_kernel(
    const unsigned short* __restrict__ qb,  // [32][2048][64] f16 (pre-scaled)
    const unsigned short* __restrict__ kb,  // [32][2048][64] f16
    const unsigned short* __restrict__ vt,  // [32][64][2048] f16 (mask-zeroed)
    const int* __restrict__ mask,           // [2][2048]
    const unsigned short* __restrict__ mb,  // [2][2048] f16 {0,1}
    float* __restrict__ out)                // [2][2048][1024]
{
    __shared__ unsigned short Ks[2][64 * 64];
    __shared__ unsigned short Vs[2][64 * 64];

    const int bh   = blockIdx.x;            // bh-major: same head -> same XCD
    const int b    = bh >> 4;
    const int h    = bh & 15;
    const int wv   = threadIdx.x >> 6;
    const int lane = threadIdx.x & 63;
    const int l15  = lane & 15;
    const int quad = lane >> 4;
    const int l7   = l15 & 7;
    const int q0w  = blockIdx.y * 128 + wv * 32;

    const unsigned short* kbh = kb + (size_t)bh * T_ * DH_;
    const unsigned short* vbh = vt + (size_t)bh * DH_ * T_;
    const unsigned short* mbb = mb + b * T_;
    const int* __restrict__ mrow = mask + b * T_;

    half8 qf[2][2];
#pragma unroll
    for (int qt = 0; qt < 2; ++qt)
#pragma unroll
        for (int c = 0; c < 2; ++c)
            qf[qt][c] = *(const half8*)(qb + ((size_t)bh * T_ + q0w + qt * 16 + l15) * DH_
                                        + c * 32 + quad * 8);

    f32x4 o[2][4];
#pragma unroll
    for (int qt = 0; qt < 2; ++qt)
#pragma unroll
        for (int n = 0; n < 4; ++n) o[qt][n] = (f32x4){0.f, 0.f, 0.f, 0.f};
    f32x4 lacc[2];
    lacc[0] = (f32x4){0.f, 0.f, 0.f, 0.f};
    lacc[1] = (f32x4){0.f, 0.f, 0.f, 0.f};

    const int lrow = lane >> 3;
    const int gch  = (lane & 7) ^ lrow;

#pragma unroll
    for (int s = 0; s < 4; ++s) {
        int j  = (wv << 2) + s;
        int rb = j & 7;
        if (j < 8) gll16(kbh + (size_t)(rb * 8 + lrow) * DH_ + gch * 8, &Ks[0][rb * 512]);
        else       gll16(vbh + (size_t)(rb * 8 + lrow) * T_  + gch * 8, &Vs[0][rb * 512]);
    }

    for (int kt = 0; kt < 32; ++kt) {
        const int cur   = kt & 1;
        const int kbase = kt * 64;
        __syncthreads();

        if (kt < 31) {
            const int nb = kbase + 64;
#pragma unroll
            for (int s = 0; s < 4; ++s) {
                int j  = (wv << 2) + s;
                int rb = j & 7;
                if (j < 8) gll16(kbh + (size_t)(nb + rb * 8 + lrow) * DH_ + gch * 8,
                                 &Ks[cur ^ 1][rb * 512]);
                else       gll16(vbh + (size_t)(rb * 8 + lrow) * T_ + nb + gch * 8,
                                 &Vs[cur ^ 1][rb * 512]);
            }
        }

        const unsigned short* Kc = &Ks[cur][0];
        const unsigned short* Vc = &Vs[cur][0];

        // K A-frags (16x16x32): K[ktile*16+l15][c*32+quad*8..]
        half8 kf[4][2];
#pragma unroll
        for (int ktile = 0; ktile < 4; ++ktile)
#pragma unroll
            for (int c = 0; c < 2; ++c)
                kf[ktile][c] = *(const half8*)(Kc + (ktile * 16 + l15) * 64
                                               + (((c * 4 + quad) ^ l7) * 8));

        // V B-frags (16x16x16): B[k=quad*4+j][n=l15]
        half4 vb[4][4];   // [n][ktile]
#pragma unroll
        for (int n = 0; n < 4; ++n)
#pragma unroll
            for (int ktile = 0; ktile < 4; ++ktile)
                vb[n][ktile] = *(const half4*)(Vc + (n * 16 + l15) * 64
                                               + (((ktile * 2 + (quad >> 1)) ^ l7) * 8)
                                               + (quad & 1) * 4);

        // mask B-frags (16x16x16, col n=0): keys ktile*16+quad*4..+3
        half4 bmf[4];
#pragma unroll
        for (int ktile = 0; ktile < 4; ++ktile) {
            half4 mv = *(const half4*)(mbb + kbase + ktile * 16 + quad * 4);
            bmf[ktile] = (l15 == 0) ? mv : (half4)0;
        }

#pragma unroll
        for (int qt = 0; qt < 2; ++qt) {
            // S^T -> exp -> in-register A-frags (half4 per ktile)
            half4 pa[4];
#pragma unroll
            for (int ktile = 0; ktile < 4; ++ktile) {
                f32x4 st = (f32x4){0.f, 0.f, 0.f, 0.f};
                st = __builtin_amdgcn_mfma_f32_16x16x32_f16(kf[ktile][0], qf[qt][0], st, 0, 0, 0);
                st = __builtin_amdgcn_mfma_f32_16x16x32_f16(kf[ktile][1], qf[qt][1], st, 0, 0, 0);
                union { uint2 u; half4 h; } cv;
                cv.u.x = pk2(__builtin_amdgcn_exp2f(st[0]), __builtin_amdgcn_exp2f(st[1]));
                cv.u.y = pk2(__builtin_amdgcn_exp2f(st[2]), __builtin_amdgcn_exp2f(st[3]));
                pa[ktile] = cv.h;
            }

            // l += P . maskvec
#pragma unroll
            for (int ktile = 0; ktile < 4; ++ktile)
                lacc[qt] = __builtin_amdgcn_mfma_f32_16x16x16f16(
                    pa[ktile], bmf[ktile], lacc[qt], 0, 0, 0);

            // O += P V
#pragma unroll
            for (int n = 0; n < 4; ++n)
#pragma unroll
                for (int ktile = 0; ktile < 4; ++ktile)
                    o[qt][n] = __builtin_amdgcn_mfma_f32_16x16x16f16(
                        pa[ktile], vb[n][ktile], o[qt][n], 0, 0, 0);
        }
    }

#pragma unroll
    for (int qt = 0; qt < 2; ++qt) {
#pragma unroll
        for (int r = 0; r < 4; ++r) {
            float lv = __shfl(lacc[qt][r], quad << 4, 64);
            int q = q0w + qt * 16 + quad * 4 + r;
            float iv = (mrow[q] != 0 && lv > 0.f) ? (1.0f / lv) : 0.f;
            float* orow = out + ((size_t)(b * T_ + q)) * C_ + h * DH_;
#pragma unroll
            for (int n = 0; n < 4; ++n)
                orow[n * 16 + l15] = o[qt][n][r] * iv;
        }
    }
}

// ---------------------------------------------------------------------------
extern "C" void kernel_launch(void* const* d_in, const int* in_sizes, int n_in,
                              void* d_out, int out_size, void* d_ws, size_t ws_size,
                              hipStream_t stream)
{
    (void)in_sizes; (void)n_in; (void)out_size; (void)ws_size;
    const float* x  = (const float*)d_in[0];
    const float* Wq = (const float*)d_in[1];
    const float* bq = (const float*)d_in[2];
    const float* Wk = (const float*)d_in[3];
    const float* bk = (const float*)d_in[4];
    const float* Wv = (const float*)d_in[5];
    const float* bv = (const float*)d_in[6];
    const int* mask = (const int*)d_in[7];
    float* out = (float*)d_out;

    const size_t NX = (size_t)B_ * T_ * C_;          // 4 Mi elements
    unsigned short* xf = (unsigned short*)d_ws;       // 8 MB fp16 x
    unsigned short* wt = xf + NX;                     // 6 MB fp16 W^T x3
    unsigned short* qb = wt + (size_t)3 * C_ * C_;    // 8 MB (pre-scaled q)
    unsigned short* kb = qb + NX;                     // 8 MB
    unsigned short* vt = kb + NX;                     // 8 MB
    unsigned short* mb = vt + NX;                     // 8 KB

    prep_kernel<<<5120, 256, 0, stream>>>(x, xf, mask, mb, Wq, Wk, Wv, wt);
    qkv_mfma_kernel<<<dim3(32, 8, 3), 256, 0, stream>>>(
        xf, wt, bq, bk, bv, mask, qb, kb, vt);
    attn_mfma_kernel<<<dim3(32, 16), 256, 0, stream>>>(qb, kb, vt, mask, mb, out);
}